// Round 4
// baseline (716.176 us; speedup 1.0000x reference)
//
#include <hip/hip_runtime.h>

#define B_CNT 4
#define N_CNT 10000
#define E_CNT 100000
#define AGG_PAIRS 24
#define AGG_BLOCKS ((B_CNT * N_CNT + AGG_PAIRS - 1) / AGG_PAIRS)  // 1667

typedef __attribute__((ext_vector_type(8))) short s16x8;
typedef __attribute__((ext_vector_type(4))) float f32x4;

__device__ __forceinline__ float b2f(unsigned short u) {
  union { unsigned int i; float f; } v; v.i = ((unsigned int)u) << 16; return v.f;
}
__device__ __forceinline__ unsigned short f2b(float f) {  // RNE (used where cheap)
  union { float f; unsigned int i; } v; v.f = f;
  unsigned int b = v.i;
  b += 0x7FFFu + ((b >> 16) & 1u);
  return (unsigned short)(b >> 16);
}
__device__ __forceinline__ unsigned short f2b_trunc(float f) {  // 1-op truncation
  union { float f; unsigned int i; } v; v.f = f;
  return (unsigned short)(v.i >> 16);
}
__device__ __forceinline__ float bhi(unsigned int u) {  // high bf16 of packed u32
  union { unsigned int i; float f; } v; v.i = u & 0xFFFF0000u; return v.f;
}
__device__ __forceinline__ float blo(unsigned int u) {  // low bf16 of packed u32
  union { unsigned int i; float f; } v; v.i = u << 16; return v.f;
}

// ---------------------------------------------------------------------------
// K_pre: fused preprocessing.
//   blocks [0,40)   : spectral transform x(4,N,16) -> xnew fp32
//   blocks [40,72)  : pack W1/W2 fp32 -> bf16 (RNE) MFMA B-fragment order
//   blocks [72,463) : per-node in-degree histogram
// ---------------------------------------------------------------------------
__global__ void k_pre(const float* __restrict__ x,
                      const float* __restrict__ tcwr,
                      const float* __restrict__ tcwi,
                      const float* __restrict__ w1,
                      const float* __restrict__ w2,
                      const int* __restrict__ eidx,
                      float* __restrict__ xnew,
                      unsigned short* __restrict__ pw1,
                      unsigned short* __restrict__ pw2,
                      int* __restrict__ cnt) {
  __shared__ float Wr[256], Wi[256];
  const int bid = blockIdx.x;
  const int t = threadIdx.x;

  if (bid < 40) {
    Wr[t] = tcwr[t * 2] + tcwr[t * 2 + 1];   // sum over MODES
    Wi[t] = tcwi[t * 2] + tcwi[t * 2 + 1];
    __syncthreads();
    const int n = bid * 256 + t;
    if (n >= N_CNT) return;
    float xt[4][16];
    for (int tt = 0; tt < 4; ++tt) {
      const float* xp = x + ((size_t)tt * N_CNT + n) * 16;
#pragma unroll
      for (int i0 = 0; i0 < 16; i0 += 4) {
        const float4 v = *(const float4*)(xp + i0);
        xt[tt][i0 + 0] = v.x; xt[tt][i0 + 1] = v.y;
        xt[tt][i0 + 2] = v.z; xt[tt][i0 + 3] = v.w;
      }
    }
    float s[16], a[16], bb[16];
#pragma unroll
    for (int i = 0; i < 16; ++i) {
      s[i]  = xt[0][i] + xt[1][i] + xt[2][i] + xt[3][i];
      a[i]  = xt[0][i] - xt[2][i];
      bb[i] = xt[1][i] - xt[3][i];
    }
    for (int o = 0; o < 16; ++o) {
      float r0 = 0.f, p = 0.f, qq = 0.f;
#pragma unroll
      for (int i = 0; i < 16; ++i) {
        const float wr = Wr[i * 16 + o], wi = Wi[i * 16 + o];
        r0 += s[i] * wr;
        p  += a[i] * wr + bb[i] * wi;
        qq += a[i] * wi - bb[i] * wr;
      }
      xnew[((size_t)0 * N_CNT + n) * 16 + o] = 0.25f * (r0 + 2.f * p);
      xnew[((size_t)1 * N_CNT + n) * 16 + o] = 0.25f * (r0 - 2.f * qq);
      xnew[((size_t)2 * N_CNT + n) * 16 + o] = 0.25f * (r0 - 2.f * p);
      xnew[((size_t)3 * N_CNT + n) * 16 + o] = 0.25f * (r0 + 2.f * qq);
    }
  } else if (bid < 72) {
    const int tg = (bid - 40) * 256 + t;  // 0..8191
    const int tile = tg >> 6, l = tg & 63, q = l >> 4, lm = l & 15;
    if (tile < 32) {
      const int nt = tile >> 2, kk = tile & 3;
      const int n = nt * 16 + lm;
      unsigned short* dst = pw1 + ((size_t)tile * 64 + l) * 8;
#pragma unroll
      for (int j = 0; j < 8; ++j) dst[j] = f2b(w1[(kk * 32 + q * 8 + j) * 128 + n]);
    } else {
      const int t2 = tile - 32;  // 0..95
      const int nt = t2 >> 2, kk = t2 & 3;
      const int n = nt * 16 + lm;
      unsigned short* dst = pw2 + ((size_t)t2 * 64 + l) * 8;
#pragma unroll
      for (int j = 0; j < 8; ++j) dst[j] = f2b(w2[(kk * 32 + q * 8 + j) * 384 + n]);
    }
  } else {
    const int e = (bid - 72) * 256 + t;
    if (e < E_CNT) atomicAdd(&cnt[eidx[E_CNT + e]], 1);
  }
}

// ---------------------------------------------------------------------------
// K_scan: exclusive prefix sum of cnt[10000] -> rowptr[10001]. One block.
// ---------------------------------------------------------------------------
__global__ void k_scan(const int* __restrict__ cnt, int* __restrict__ rowptr) {
  __shared__ int part[256];
  const int t = threadIdx.x;
  const int base = t * 40;
  int s = 0;
  for (int k = 0; k < 40; ++k) {
    const int idx = base + k;
    s += (idx < N_CNT) ? cnt[idx] : 0;
  }
  part[t] = s;
  __syncthreads();
  for (int off = 1; off < 256; off <<= 1) {
    const int v = (t >= off) ? part[t - off] : 0;
    __syncthreads();
    part[t] += v;
    __syncthreads();
  }
  int run = (t > 0) ? part[t - 1] : 0;
  for (int k = 0; k < 40; ++k) {
    const int idx = base + k;
    if (idx < N_CNT) { rowptr[idx] = run; run += cnt[idx]; }
  }
  if (t == 255) rowptr[N_CNT] = part[255];
}

// ---------------------------------------------------------------------------
// K_fill: scatter edge ids into dst-sorted order. perm[sorted_pos] = edge id.
// ---------------------------------------------------------------------------
__global__ void k_fill(const int* __restrict__ eidx, const int* __restrict__ rowptr,
                       int* __restrict__ cursor, int* __restrict__ perm) {
  const int e = blockIdx.x * 256 + threadIdx.x;
  if (e < E_CNT) {
    const int d = eidx[E_CNT + e];
    const int pos = atomicAdd(&cursor[d], 1);
    perm[rowptr[d] + pos] = e;
  }
}

// ---------------------------------------------------------------------------
// K_edge v4: per block: 32 dst-sorted edges, one batch.
//   GEMM1: H(32x128) = relu(EA @ W1 + b1)   (MFMA, A gathered, perm-packed bf16)
//   GEMM2: EW(32x384) = H @ W2 + b2         (MFMA; EW stored TRANSPOSED in LDS)
//   phase3: per-edge message -> bf16 pout in LDS
//   phase3.5: segmented reduce over equal-dst runs -> fp32 atomicAdd into sums
// LDS: EWs region (25088 B) unions Hs (8704 B); + xgs/shs/pout/dsts/lens ~31 KB
// ---------------------------------------------------------------------------
__global__ __launch_bounds__(256, 5) void k_edge(
    const float* __restrict__ ea, const int* __restrict__ eidx,
    const float* __restrict__ esh, const int* __restrict__ perm,
    const unsigned short* __restrict__ pw1, const unsigned short* __restrict__ pw2,
    const float* __restrict__ b1v, const float* __restrict__ b2v,
    const float* __restrict__ xnew, float* __restrict__ sums) {
  __shared__ __align__(16) unsigned short EWs[32 * 392];  // unions Hs[32*136]
  __shared__ __align__(16) float xgs[32 * 20];            // 16 + 4 pad
  __shared__ float shs[32 * 4];
  __shared__ __align__(16) unsigned short pout[32 * 42];  // 40 + 2 pad, bf16
  __shared__ int dsts[32];
  __shared__ int lens[32];

  const int t = threadIdx.x;
  const int b = blockIdx.y;
  const int e0 = blockIdx.x * 32;
  const int w = t >> 6, l = t & 63, q = l >> 4, lm = l & 15;

  // ---- phase 0: stage xg (double-indirect gather), sh, dst ----
  if (t < 128) {
    const int el = t >> 2, i0 = (t & 3) * 4;
    const int sid = perm[e0 + el];
    const int src = eidx[sid];
    const float4 v = *(const float4*)(xnew + ((size_t)b * N_CNT + src) * 16 + i0);
    xgs[el * 20 + i0 + 0] = v.x;
    xgs[el * 20 + i0 + 1] = v.y;
    xgs[el * 20 + i0 + 2] = v.z;
    xgs[el * 20 + i0 + 3] = v.w;
  } else if (t < 160) {
    const int el = t - 128;
    const int sid = perm[e0 + el];
    const float4 v = *(const float4*)(esh + ((size_t)b * E_CNT + sid) * 4);
    shs[el * 4 + 0] = v.x;
    shs[el * 4 + 1] = v.y;
    shs[el * 4 + 2] = v.z;
    shs[el * 4 + 3] = v.w;
  } else if (t < 192) {
    const int el = t - 160;
    dsts[el] = eidx[E_CNT + perm[e0 + el]];
  }

  // ---- GEMM1 ----
  f32x4 acc1[2][2];
#pragma unroll
  for (int mt = 0; mt < 2; ++mt)
#pragma unroll
    for (int j = 0; j < 2; ++j) acc1[mt][j] = (f32x4)0.0f;

  const float* eab = ea + (size_t)b * E_CNT * 128;
  const float* arow[2] = { eab + (size_t)perm[e0 + lm] * 128,
                           eab + (size_t)perm[e0 + 16 + lm] * 128 };
#pragma unroll
  for (int kk = 0; kk < 4; ++kk) {
    const s16x8 bf0 = *(const s16x8*)(pw1 + (((size_t)(2 * w + 0) * 4 + kk) * 64 + l) * 8);
    const s16x8 bf1 = *(const s16x8*)(pw1 + (((size_t)(2 * w + 1) * 4 + kk) * 64 + l) * 8);
#pragma unroll
    for (int mt = 0; mt < 2; ++mt) {
      const unsigned int* ap = (const unsigned int*)(arow[mt] + kk * 32 + q * 8);
      const uint4 a0 = *(const uint4*)ap;
      const uint4 a1 = *(const uint4*)(ap + 4);
      // pack fp32 pairs -> bf16x2 by truncation (v_perm_b32, 1 op / 2 elems)
      uint4 pk;
      pk.x = __builtin_amdgcn_perm(a0.y, a0.x, 0x07060302u);
      pk.y = __builtin_amdgcn_perm(a0.w, a0.z, 0x07060302u);
      pk.z = __builtin_amdgcn_perm(a1.y, a1.x, 0x07060302u);
      pk.w = __builtin_amdgcn_perm(a1.w, a1.z, 0x07060302u);
      union { uint4 u; s16x8 v; } cvt; cvt.u = pk;
      acc1[mt][0] = __builtin_amdgcn_mfma_f32_16x16x32_bf16(cvt.v, bf0, acc1[mt][0], 0, 0, 0);
      acc1[mt][1] = __builtin_amdgcn_mfma_f32_16x16x32_bf16(cvt.v, bf1, acc1[mt][1], 0, 0, 0);
    }
  }
  // Hs lives in the first 8704 B of EWs. Hs[row][n] @ EWs[row*136 + n]
#pragma unroll
  for (int j = 0; j < 2; ++j) {
    const int n = (2 * w + j) * 16 + lm;
    const float bias = b1v[n];
#pragma unroll
    for (int mt = 0; mt < 2; ++mt)
#pragma unroll
      for (int r = 0; r < 4; ++r) {
        const float v = fmaxf(acc1[mt][j][r] + bias, 0.0f);
        EWs[(mt * 16 + q * 4 + r) * 136 + n] = f2b_trunc(v);
      }
  }
  __syncthreads();  // barrier 1: Hs ready

  // ---- GEMM2 (A from Hs region) ----
  f32x4 acc2[2][6];
#pragma unroll
  for (int mt = 0; mt < 2; ++mt)
#pragma unroll
    for (int jj = 0; jj < 6; ++jj) acc2[mt][jj] = (f32x4)0.0f;

#pragma unroll
  for (int kk = 0; kk < 4; ++kk) {
    s16x8 bw[6];
#pragma unroll
    for (int jj = 0; jj < 6; ++jj)
      bw[jj] = *(const s16x8*)(pw2 + (((size_t)(6 * w + jj) * 4 + kk) * 64 + l) * 8);
#pragma unroll
    for (int mt = 0; mt < 2; ++mt) {
      const s16x8 ah = *(const s16x8*)(&EWs[(mt * 16 + lm) * 136 + kk * 32 + q * 8]);
#pragma unroll
      for (int jj = 0; jj < 6; ++jj)
        acc2[mt][jj] = __builtin_amdgcn_mfma_f32_16x16x32_bf16(ah, bw[jj], acc2[mt][jj], 0, 0, 0);
    }
  }
  __syncthreads();  // barrier 2: all Hs reads done; EWs region may be overwritten

  // ---- EW epilogue: TRANSPOSED store ----
  // w1 part (flat ch n2<256, n2=i*16+o): store at [m][o*16+i], o=lm, i=6w+jj
  // w2 part (n2>=256, r2=i*8+oo):        store at [m][256+oo*16+i]
#pragma unroll
  for (int jj = 0; jj < 6; ++jj) {
    const int ich = 6 * w + jj;
    const int n2 = ich * 16 + lm;
    const float bias = b2v[n2];
    int dcol;
    if (ich < 16) {
      dcol = lm * 16 + ich;
    } else {
      const int t2 = ich - 16;                 // 0..7
      dcol = 256 + (lm & 7) * 16 + t2 * 2 + (lm >> 3);
    }
#pragma unroll
    for (int mt = 0; mt < 2; ++mt)
#pragma unroll
      for (int r = 0; r < 4; ++r) {
        const int m = mt * 16 + q * 4 + r;
        EWs[m * 392 + dcol] = f2b_trunc(acc2[mt][jj][r] + bias);
      }
  }
  __syncthreads();  // barrier 3: EW ready

  // ---- phase 3: messages (8 threads/edge, 5 ch each) -> bf16 pout ----
  {
    const int m = t >> 3;
    const int sub = t & 7;
    float xr[16];
#pragma unroll
    for (int i0 = 0; i0 < 16; i0 += 4) {
      const float4 v = *(const float4*)(&xgs[m * 20 + i0]);
      xr[i0 + 0] = v.x; xr[i0 + 1] = v.y; xr[i0 + 2] = v.z; xr[i0 + 3] = v.w;
    }
    const float sh0v = shs[m * 4 + 0];
    const int c0 = sub * 5;
#pragma unroll
    for (int cc = 0; cc < 5; ++cc) {
      const int c = c0 + cc;
      int base;
      float mul;
      if (c < 16) {
        base = m * 392 + c * 16;
        mul = 0.25f * sh0v;  // ALPHA = 1/sqrt(16)
      } else {
        const int cr = c - 16;
        const int oo = cr / 3;
        const int md = cr - oo * 3;
        base = m * 392 + 256 + oo * 16;
        mul = 0.25f * shs[m * 4 + 1 + md];
      }
      const uint4 g0 = *(const uint4*)(&EWs[base]);
      const uint4 g1 = *(const uint4*)(&EWs[base + 8]);
      float accv;
      accv  = xr[0]  * blo(g0.x) + xr[1]  * bhi(g0.x);
      accv += xr[2]  * blo(g0.y) + xr[3]  * bhi(g0.y);
      accv += xr[4]  * blo(g0.z) + xr[5]  * bhi(g0.z);
      accv += xr[6]  * blo(g0.w) + xr[7]  * bhi(g0.w);
      accv += xr[8]  * blo(g1.x) + xr[9]  * bhi(g1.x);
      accv += xr[10] * blo(g1.y) + xr[11] * bhi(g1.y);
      accv += xr[12] * blo(g1.z) + xr[13] * bhi(g1.z);
      accv += xr[14] * blo(g1.w) + xr[15] * bhi(g1.w);
      pout[m * 42 + c] = f2b(accv * mul);
    }
  }

  // ---- phase 3.5: run-length detect + segmented reduce + atomic scatter ----
  if (t < 32) {
    const int d = dsts[t];
    int L = 0;
    if (t == 0 || dsts[t - 1] != d) {
      int k = t;
      while (k < 32 && dsts[k] == d) ++k;
      L = k - t;
    }
    lens[t] = L;
  }
  __syncthreads();  // barrier 4: pout + lens ready
  {
    const int m = t >> 3;
    const int sub = t & 7;
    const int L = lens[m];
    if (L > 0) {
      float* gp = sums + ((size_t)b * N_CNT + dsts[m]) * 40;
      const int c0 = sub * 5;
#pragma unroll
      for (int cc = 0; cc < 5; ++cc) {
        const int c = c0 + cc;
        float s = 0.f;
        for (int k = 0; k < L; ++k) s += b2f(pout[(m + k) * 42 + c]);
        atomicAdd(gp + c, s);
      }
    }
  }
}

// ---------------------------------------------------------------------------
// K_agg: BN partials from sums/deg. 24 (b,node) pairs per block; 240 lanes
// as (sub 0..5, channel 0..39). No aggbuf — k_out re-divides.
// ---------------------------------------------------------------------------
__global__ __launch_bounds__(256) void k_agg(
    const float* __restrict__ sums, const int* __restrict__ cnt,
    float* __restrict__ pbuf) {
  __shared__ float rs[240], rq[240];
  const int t = threadIdx.x;
  if (t < 240) {
    const int sub = t / 40, c = t - sub * 40;
    float bs = 0.f, bq = 0.f;
#pragma unroll
    for (int j = 0; j < 4; ++j) {
      const int p = blockIdx.x * AGG_PAIRS + j * 6 + sub;
      if (p < B_CNT * N_CNT) {
        const int n = p % N_CNT;
        const float dg = fmaxf((float)cnt[n], 1.f);
        const float v = sums[(size_t)p * 40 + c] / dg;
        bs += v; bq += v * v;
      }
    }
    rs[sub * 40 + c] = bs;
    rq[sub * 40 + c] = bq;
  }
  __syncthreads();
  if (t < 40) {
    float s0 = 0.f, q0 = 0.f;
#pragma unroll
    for (int j = 0; j < 6; ++j) { s0 += rs[j * 40 + t]; q0 += rq[j * 40 + t]; }
    pbuf[(size_t)blockIdx.x * 80 + t] = s0;
    pbuf[(size_t)blockIdx.x * 80 + 40 + t] = q0;
  }
}

// ---------------------------------------------------------------------------
// K_stats: reduce per-block BN partials, finalize scale/shift. One block.
// ---------------------------------------------------------------------------
__global__ void k_stats(const float* __restrict__ pbuf,
                        const float* __restrict__ gma, const float* __restrict__ bta,
                        float* __restrict__ scalev, float* __restrict__ shiftv) {
  __shared__ float red[240];
  const int t = threadIdx.x;
  if (t < 240) {
    const int seg = t / 80, col = t - seg * 80;
    const int j0 = seg * 556;
    const int j1 = (j0 + 556 < AGG_BLOCKS) ? (j0 + 556) : AGG_BLOCKS;
    float s = 0.f;
    for (int j = j0; j < j1; ++j) s += pbuf[(size_t)j * 80 + col];
    red[seg * 80 + col] = s;
  }
  __syncthreads();
  if (t < 40) {
    const float inv = 1.0f / (float)(B_CNT * N_CNT);
    const float su = red[t] + red[80 + t] + red[160 + t];
    const float sq = red[40 + t] + red[120 + t] + red[200 + t];
    const float mu = su * inv;
    const float var = fmaxf(sq * inv - mu * mu, 0.f);
    const float sc = rsqrtf(var + 1e-5f) * gma[t];
    scalev[t] = sc;
    shiftv[t] = bta[t] - mu * sc;
  }
}

// ---------------------------------------------------------------------------
// K_out: out = (sums/deg) * scale + shift, fp32.
// ---------------------------------------------------------------------------
__global__ void k_out(const float* __restrict__ sums, const int* __restrict__ cnt,
                      const float* __restrict__ scalev, const float* __restrict__ shiftv,
                      float* __restrict__ outp) {
  __shared__ float sc[40], sh[40];
  const int t = threadIdx.x;
  if (t < 40) { sc[t] = scalev[t]; sh[t] = shiftv[t]; }
  __syncthreads();
  const unsigned base = blockIdx.x * 1024u + t;
#pragma unroll
  for (int k2 = 0; k2 < 4; ++k2) {
    const unsigned idx = base + k2 * 256u;
    if (idx < 1600000u) {
      const unsigned row = idx / 40u;
      const unsigned ch = idx - row * 40u;
      const unsigned node = row % 10000u;
      const float dg = fmaxf((float)cnt[node], 1.f);
      outp[idx] = (sums[idx] / dg) * sc[ch] + sh[ch];
    }
  }
}

// ---------------------------------------------------------------------------
// Workspace layout (bytes), total ~10.1 MB:
//   [0)           sums      6,400,000   (zeroed)
//   [6,400,000)   cnt          40,000   (zeroed)
//   [6,440,000)   cursor       40,000   (zeroed)
//   [6,480,000)   xnew      2,560,000
//   [9,040,000)   pw1          32,768
//   [9,072,768)   pw2          98,304
//   [9,171,072)   rowptr       40,016
//   [9,211,088)   perm        400,000
//   [9,611,088)   pbuf        533,440   (1667 * 80 floats)
//   [10,144,528)  scalev          160
//   [10,144,688)  shiftv          160
// ---------------------------------------------------------------------------
extern "C" void kernel_launch(void* const* d_in, const int* in_sizes, int n_in,
                              void* d_out, int out_size, void* d_ws, size_t ws_size,
                              hipStream_t stream) {
  (void)in_sizes; (void)n_in; (void)out_size; (void)ws_size;
  const float* x    = (const float*)d_in[0];
  const int*   eidx = (const int*)d_in[1];
  const float* ea   = (const float*)d_in[2];
  const float* esh  = (const float*)d_in[3];
  const float* tcwr = (const float*)d_in[4];
  const float* tcwi = (const float*)d_in[5];
  const float* w1   = (const float*)d_in[6];
  const float* b1   = (const float*)d_in[7];
  const float* w2   = (const float*)d_in[8];
  const float* b2   = (const float*)d_in[9];
  const float* gma  = (const float*)d_in[10];
  const float* bta  = (const float*)d_in[11];

  char* ws = (char*)d_ws;
  float*          sums   = (float*)(ws + 0);
  int*            cnt    = (int*)(ws + 6400000);
  int*            cursor = (int*)(ws + 6440000);
  float*          xnew   = (float*)(ws + 6480000);
  unsigned short* pw1    = (unsigned short*)(ws + 9040000);
  unsigned short* pw2    = (unsigned short*)(ws + 9072768);
  int*            rowptr = (int*)(ws + 9171072);
  int*            perm   = (int*)(ws + 9211088);
  float*          pbuf   = (float*)(ws + 9611088);
  float*          scalev = (float*)(ws + 10144528);
  float*          shiftv = (float*)(ws + 10144688);

  hipMemsetAsync(ws, 0, 6480000, stream);  // sums + cnt + cursor
  k_pre<<<dim3(463), dim3(256), 0, stream>>>(x, tcwr, tcwi, w1, w2, eidx,
                                             xnew, pw1, pw2, cnt);
  k_scan<<<dim3(1), dim3(256), 0, stream>>>(cnt, rowptr);
  k_fill<<<dim3(391), dim3(256), 0, stream>>>(eidx, rowptr, cursor, perm);
  k_edge<<<dim3(E_CNT / 32, B_CNT), dim3(256), 0, stream>>>(
      ea, eidx, esh, perm, pw1, pw2, b1, b2, xnew, sums);
  k_agg<<<dim3(AGG_BLOCKS), dim3(256), 0, stream>>>(sums, cnt, pbuf);
  k_stats<<<dim3(1), dim3(256), 0, stream>>>(pbuf, gma, bta, scalev, shiftv);
  k_out<<<dim3(1563), dim3(256), 0, stream>>>(sums, cnt, scalev, shiftv,
                                              (float*)d_out);
}